// Round 5
// baseline (457.767 us; speedup 1.0000x reference)
//
#include <hip/hip_runtime.h>

typedef __attribute__((ext_vector_type(8))) short short8;
typedef __attribute__((ext_vector_type(4))) float floatx4;
typedef unsigned short ushort_t;
typedef unsigned int uint32;

// ---------- helpers ----------

__device__ __forceinline__ uint32 f2bf_bits(float f) {
  uint32 u = __builtin_bit_cast(uint32, f);
  u += 0x7fffu + ((u >> 16) & 1u);   // round-to-nearest-even
  return u >> 16;
}

__device__ __forceinline__ float tanh_fast(float x) {
  float e = __expf(2.0f * x);
  return 1.0f - 2.0f * __builtin_amdgcn_rcpf(e + 1.0f);
}

#define MFMA16(a, b, c) __builtin_amdgcn_mfma_f32_16x16x32_bf16((a), (b), (c), 0, 0, 0)

// lgkm-only barrier: __syncthreads() drains vmcnt(0) (kills in-flight HBM/L2
// prefetch every group). All cross-wave dataflow here is via LDS, so
// lgkmcnt(0) + s_barrier is sufficient for correctness.
#define BAR_LGKM() asm volatile("s_waitcnt lgkmcnt(0)\n\ts_barrier" ::: "memory")

// ---------- prep: fold weights, cast bf16, emit FRAGMENT-MAJOR layouts ----------
// Wtm2 panels: p = (g*8 + nb)*8 + kk          (nb: n-tile of 16, kk: k-chunk of 32)
//   offset kh*128 + l15*8 + e  <-  W_mid[g][i][o]*w_inp[g][i],
//   o = nb*16 + l15, i = kk*32 + kh*8 + e     (512 ushorts = 1 KB per panel)
// Wtr2 panels: q = (g*16 + nb)*4 + kk2
//   offset kh*128 + l15*8 + e  <-  W_root[k][o],
//   o = nb*16 + l15, k = g*128 + kk2*32 + kh*8 + e
//
// ws layout: Wtm2 1MB @0 | Wtr2 1MB @1MB | bias_eff @2MB | part @4MB

__global__ __launch_bounds__(256) void prep(const float* __restrict__ w_inp,
                                            const float* __restrict__ pbias,
                                            const float* __restrict__ W_mid,
                                            const float* __restrict__ b_mid,
                                            const float* __restrict__ W_root,
                                            ushort_t* __restrict__ Wtm2,
                                            ushort_t* __restrict__ Wtr2,
                                            float* __restrict__ bias_eff) {
  __shared__ float tl[32][33];
  __shared__ float red[256];
  const int b = blockIdx.x, t = threadIdx.x;
  const int tx = t & 31, ty = t >> 5;              // load-phase coords

  if (b < 512) {
    // per-g 256(i) x 128(o), 32x32 tiles: coalesced load+fold, frag-major store
    const int g = b >> 5, tile = b & 31;
    const int i0 = (tile >> 2) * 32, o0 = (tile & 3) * 32;
#pragma unroll
    for (int r = 0; r < 4; ++r) {
      const int il = ty * 4 + r;
      tl[il][tx] = W_mid[(g << 15) + (i0 + il) * 128 + o0 + tx] * w_inp[g * 256 + i0 + il];
    }
    __syncthreads();
    const int nl = t >> 3, s = t & 7;              // store-phase coords
    const int o = o0 + nl, nb = o >> 4, l15 = o & 15;
    const int kk = i0 >> 5;                        // i0 is 32-aligned
    const int iloc = s * 4, kh = iloc >> 3, e0 = iloc & 7;
    const uint32 lo = (uint32)f2bf_bits(tl[iloc + 0][nl]) |
                      ((uint32)f2bf_bits(tl[iloc + 1][nl]) << 16);
    const uint32 hi = (uint32)f2bf_bits(tl[iloc + 2][nl]) |
                      ((uint32)f2bf_bits(tl[iloc + 3][nl]) << 16);
    uint2* dst = (uint2*)(Wtm2 + (size_t)(((g * 8 + nb) * 8 + kk) * 512 + kh * 128 + l15 * 8 + e0));
    *dst = make_uint2(lo, hi);
  } else if (b < 1024) {
    // 2048(k) x 256(o), 32x32 tiles
    const int bb = b - 512;
    const int k0 = (bb >> 3) * 32, o0 = (bb & 7) * 32;
#pragma unroll
    for (int r = 0; r < 4; ++r) {
      const int kl = ty * 4 + r;
      tl[kl][tx] = W_root[(k0 + kl) * 256 + o0 + tx];
    }
    __syncthreads();
    const int nl = t >> 3, s = t & 7;
    const int o = o0 + nl, nb = o >> 4, l15 = o & 15;
    const int g = k0 >> 7, kk2 = (k0 >> 5) & 3;    // k0 is 32-aligned
    const int iloc = s * 4, kh = iloc >> 3, e0 = iloc & 7;
    const uint32 lo = (uint32)f2bf_bits(tl[iloc + 0][nl]) |
                      ((uint32)f2bf_bits(tl[iloc + 1][nl]) << 16);
    const uint32 hi = (uint32)f2bf_bits(tl[iloc + 2][nl]) |
                      ((uint32)f2bf_bits(tl[iloc + 3][nl]) << 16);
    uint2* dst = (uint2*)(Wtr2 + (size_t)(((g * 16 + nb) * 4 + kk2) * 512 + kh * 128 + l15 * 8 + e0));
    *dst = make_uint2(lo, hi);
  } else {
    // bias_eff[g][o] = b_mid[g][o] + sum_i pbias[g*4 + i>>6] * W_mid[g][i][o]
    const int g = b - 1024;
    const int o = t & 127, ih = t >> 7;
    const float* wp = W_mid + (g << 15) + ih * 128 * 128 + o;
    const float pb0 = pbias[g * 4 + ih * 2];
    const float pb1 = pbias[g * 4 + ih * 2 + 1];
    float s = 0.f;
#pragma unroll 8
    for (int ii = 0; ii < 128; ++ii) s += (ii < 64 ? pb0 : pb1) * wp[ii * 128];
    red[t] = s;
    __syncthreads();
    if (ih == 0) bias_eff[g * 128 + o] = b_mid[g * 128 + o] + red[o] + red[128 + o];
  }
}

// ---------- fused mid+root ----------
// v5: M=64, 8 waves, split-K x2, grid 512 — HARD 128-VGPR cap
// (__launch_bounds__(512,4)) so 2 blocks/CU are actually resident (v4 was ~135
// VGPR -> 1 block/CU -> barrier convoy fully exposed). VGPR diet via
// wave-uniform weight bases (SGPR) + single lane voffset. Mid B ring deepened
// to distance 4 (covers L2 latency). Per-group issue order gives only counted
// vmcnt waits: midB -> rootB -> bias -> conv(rx g) -> issue rx(g+1) -> BAR ->
// mid -> epi -> BAR -> root. No wait ever drains the x prefetch.

template <bool SPLIT>
__global__ __launch_bounds__(512, 4) void fused(const float* __restrict__ x,
                                                const ushort_t* __restrict__ Wtm2,
                                                const ushort_t* __restrict__ Wtr2,
                                                const float* __restrict__ bias_eff,
                                                const float* __restrict__ b_root,
                                                float* __restrict__ dst) {
  constexpr int GROUPS = SPLIT ? 8 : 16;

  __shared__ __align__(16) ushort_t sX[64 * 264];   // 33.8 KB
  __shared__ __align__(16) ushort_t sMid[64 * 136]; // 17.4 KB

  const int t = threadIdx.x;
  const int lane = t & 63;
  const int w = __builtin_amdgcn_readfirstlane(t >> 6);   // wave 0..7
  const int tile = SPLIT ? (int)(blockIdx.x >> 1) : (int)blockIdx.x;
  const int h = SPLIT ? (int)(blockIdx.x & 1) : 0;
  const int G0 = h * 8;
  const int m0 = tile * 64;
  const int l15 = lane & 15;
  const int kh = lane >> 4;          // 0..3

  // x staging: thread t handles row xr = t>>3 (0..63), float4-slot xq = t&7
  const int xr = t >> 3, xq = t & 7;
  const float* xbase = x + (size_t)(m0 + xr) * 4096 + (size_t)G0 * 256 + xq * 4;
  uint32* sxw = (uint32*)(sX + xr * 264 + xq * 4);

  // A-frag LDS read bases
  const ushort_t* sxa = sX + l15 * 264 + kh * 8;    // + af*16*264 + kk*32
  const ushort_t* sma = sMid + l15 * 136 + kh * 8;  // + af*16*136 + kk2*32

  // wave-uniform weight bases (SGPR) + one per-lane element offset
  const ushort_t* wtm_u = Wtm2 + (((size_t)G0) << 15) + w * 4096;  // + g*32768 + kk*512 + wlo
  const ushort_t* wtr_u = Wtr2 + (((size_t)G0) << 15) + w * 4096;  // + g*32768 + (ni*4+kk2)*512 + wlo
  const int wlo = lane * 8;

  float4 rx[8];
  floatx4 racc[4][2] = {};

  // prologue: x for local group 0
#pragma unroll
  for (int p = 0; p < 8; ++p) rx[p] = *(const float4*)(xbase + p * 32);

#pragma unroll 1
  for (int g = 0; g < GROUPS; ++g) {
    const int gw = g << 15;

    // ---- issue this group's weight loads first (counted waits only) ----
    short8 mb[4];
#pragma unroll
    for (int kk = 0; kk < 4; ++kk) mb[kk] = *(const short8*)(wtm_u + gw + kk * 512 + wlo);
    short8 rb[2][2];
#pragma unroll
    for (int ni = 0; ni < 2; ++ni) rb[0][ni] = *(const short8*)(wtr_u + gw + (ni * 4 + 0) * 512 + wlo);
#pragma unroll
    for (int ni = 0; ni < 2; ++ni) rb[1][ni] = *(const short8*)(wtr_u + gw + (ni * 4 + 1) * 512 + wlo);
    const float bias = bias_eff[(G0 + g) * 128 + w * 16 + l15];

    // ---- convert rx (group g) -> sX, round-half-up + byte-perm pack ----
#pragma unroll
    for (int p = 0; p < 8; ++p) {
      uint32 bx = __builtin_bit_cast(uint32, rx[p].x) + 0x8000u;
      uint32 by = __builtin_bit_cast(uint32, rx[p].y) + 0x8000u;
      uint32 bz = __builtin_bit_cast(uint32, rx[p].z) + 0x8000u;
      uint32 bw = __builtin_bit_cast(uint32, rx[p].w) + 0x8000u;
      uint32 lo = __builtin_amdgcn_perm(by, bx, 0x07060302u);
      uint32 hi = __builtin_amdgcn_perm(bw, bz, 0x07060302u);
      *(uint2*)(sxw + p * 16) = make_uint2(lo, hi);
    }

    // ---- prefetch next group's x (issued AFTER conv read rx: regs reused,
    //      and it is the youngest vmem so no later counted wait drains it) ----
    if (g < GROUPS - 1) {
      const float* xn = xbase + (g + 1) * 256;
#pragma unroll
      for (int p = 0; p < 8; ++p) rx[p] = *(const float4*)(xn + p * 32);
    }
    __builtin_amdgcn_sched_barrier(0);  // keep rx issue here (not sunk past epilogue)

    BAR_LGKM();  // (B) sX ready; also sX WAR safe (all waves past mid(g-1) via C)

    // ---- mid GEMM: 64x16 per wave (4 row-frags x 1 n-frag), K=256 ----
    // B ring distance 4: load for kk+4 issued at kk -> ~4 iterations of cover.
    floatx4 macc[4] = {};
#pragma unroll
    for (int kk = 0; kk < 8; ++kk) {
      short8 a0 = *(const short8*)(sxa + 0 * 16 * 264 + kk * 32);
      short8 a1 = *(const short8*)(sxa + 1 * 16 * 264 + kk * 32);
      short8 a2 = *(const short8*)(sxa + 2 * 16 * 264 + kk * 32);
      short8 a3 = *(const short8*)(sxa + 3 * 16 * 264 + kk * 32);
      short8 b = mb[kk & 3];
      if (kk < 4) mb[kk & 3] = *(const short8*)(wtm_u + gw + (kk + 4) * 512 + wlo);
      macc[0] = MFMA16(a0, b, macc[0]);
      macc[1] = MFMA16(a1, b, macc[1]);
      macc[2] = MFMA16(a2, b, macc[2]);
      macc[3] = MFMA16(a3, b, macc[3]);
    }

    // ---- epilogue: bias + tanh -> sMid (bf16, root-A layout) ----
    {
      const int col = w * 16 + l15;
#pragma unroll
      for (int af = 0; af < 4; ++af)
#pragma unroll
        for (int r = 0; r < 4; ++r) {
          const int row = af * 16 + kh * 4 + r;
          sMid[row * 136 + col] = (ushort_t)f2bf_bits(tanh_fast(macc[af][r] + bias));
        }
    }

    BAR_LGKM();  // (C) sMid ready

    // ---- root partial: 64x32 per wave (4 row-frags x 2 n-frags), K=128 ----
#pragma unroll
    for (int kk2 = 0; kk2 < 4; ++kk2) {
      short8 a0 = *(const short8*)(sma + 0 * 16 * 136 + kk2 * 32);
      short8 a1 = *(const short8*)(sma + 1 * 16 * 136 + kk2 * 32);
      short8 a2 = *(const short8*)(sma + 2 * 16 * 136 + kk2 * 32);
      short8 a3 = *(const short8*)(sma + 3 * 16 * 136 + kk2 * 32);
      short8 b0 = rb[kk2 & 1][0], b1 = rb[kk2 & 1][1];
      if (kk2 < 2) {  // stream rounds 2,3; no dead tail loads
#pragma unroll
        for (int ni = 0; ni < 2; ++ni)
          rb[kk2 & 1][ni] = *(const short8*)(wtr_u + gw + (ni * 4 + kk2 + 2) * 512 + wlo);
      }
      racc[0][0] = MFMA16(a0, b0, racc[0][0]);
      racc[0][1] = MFMA16(a0, b1, racc[0][1]);
      racc[1][0] = MFMA16(a1, b0, racc[1][0]);
      racc[1][1] = MFMA16(a1, b1, racc[1][1]);
      racc[2][0] = MFMA16(a2, b0, racc[2][0]);
      racc[2][1] = MFMA16(a2, b1, racc[2][1]);
      racc[3][0] = MFMA16(a3, b0, racc[3][0]);
      racc[3][1] = MFMA16(a3, b1, racc[3][1]);
    }
  }

  // ---- final store ----
  float* o = SPLIT ? dst + (size_t)h * (16384 * 256) : dst;
#pragma unroll
  for (int ni = 0; ni < 2; ++ni) {
    const int col = w * 32 + ni * 16 + l15;
    const float br = SPLIT ? 0.0f : b_root[col];
#pragma unroll
    for (int af = 0; af < 4; ++af)
#pragma unroll
      for (int r = 0; r < 4; ++r) {
        const int row = m0 + af * 16 + kh * 4 + r;
        o[(size_t)row * 256 + col] = racc[af][ni][r] + br;
      }
  }
}

// ---------- split-K reduce: out = p0 + p1 + b_root ----------

__global__ __launch_bounds__(256) void reducek(const float* __restrict__ part,
                                               const float* __restrict__ b_root,
                                               float* __restrict__ out) {
  const int i = blockIdx.x * 256 + threadIdx.x;   // float4 index, 1,048,576 total
  float4 a = ((const float4*)part)[i];
  float4 c = ((const float4*)(part + (size_t)16384 * 256))[i];
  float4 br = ((const float4*)b_root)[i & 63];
  float4 r;
  r.x = a.x + c.x + br.x;
  r.y = a.y + c.y + br.y;
  r.z = a.z + c.z + br.z;
  r.w = a.w + c.w + br.w;
  ((float4*)out)[i] = r;
}

// ---------- launch ----------

extern "C" void kernel_launch(void* const* d_in, const int* in_sizes, int n_in,
                              void* d_out, int out_size, void* d_ws, size_t ws_size,
                              hipStream_t stream) {
  const float* x      = (const float*)d_in[0];
  const float* w_inp  = (const float*)d_in[1];
  const float* pbias  = (const float*)d_in[2];
  const float* W_mid  = (const float*)d_in[3];
  const float* b_mid  = (const float*)d_in[4];
  const float* W_root = (const float*)d_in[5];
  const float* b_root = (const float*)d_in[6];
  float* out = (float*)d_out;

  char* ws = (char*)d_ws;
  ushort_t* Wtm2     = (ushort_t*)(ws);
  ushort_t* Wtr2     = (ushort_t*)(ws + (1 << 20));
  float*    bias_eff = (float*)   (ws + (2 << 20));
  float*    part     = (float*)   (ws + (4 << 20));

  const size_t need = (size_t)(4 << 20) + 2ull * 16384 * 256 * 4;
  const bool split = ws_size >= need;

  prep<<<dim3(1040), dim3(256), 0, stream>>>(w_inp, pbias, W_mid, b_mid, W_root, Wtm2, Wtr2, bias_eff);
  if (split) {
    fused<true><<<dim3(512), dim3(512), 0, stream>>>(x, Wtm2, Wtr2, bias_eff, b_root, part);
    reducek<<<dim3(4096), dim3(256), 0, stream>>>(part, b_root, out);
  } else {
    fused<false><<<dim3(256), dim3(512), 0, stream>>>(x, Wtm2, Wtr2, bias_eff, b_root, out);
  }
}

// Round 6
// 390.998 us; speedup vs baseline: 1.1708x; 1.1708x over previous
//
#include <hip/hip_runtime.h>

typedef __attribute__((ext_vector_type(8))) short short8;
typedef __attribute__((ext_vector_type(4))) float floatx4;
typedef unsigned short ushort_t;
typedef unsigned int uint32;

// ---------- helpers ----------

__device__ __forceinline__ uint32 f2bf_bits(float f) {
  uint32 u = __builtin_bit_cast(uint32, f);
  u += 0x7fffu + ((u >> 16) & 1u);   // round-to-nearest-even
  return u >> 16;
}

__device__ __forceinline__ float tanh_fast(float x) {
  float e = __expf(2.0f * x);
  return 1.0f - 2.0f * __builtin_amdgcn_rcpf(e + 1.0f);
}

#define MFMA16(a, b, c) __builtin_amdgcn_mfma_f32_16x16x32_bf16((a), (b), (c), 0, 0, 0)

// lgkm-only barrier: __syncthreads() drains vmcnt(0) (kills in-flight HBM/L2
// prefetch every group). All cross-wave dataflow here is via LDS, so
// lgkmcnt(0) + s_barrier is sufficient for correctness.
#define BAR_LGKM() asm volatile("s_waitcnt lgkmcnt(0)\n\ts_barrier" ::: "memory")

// ---------- prep: fold weights, cast bf16, emit FRAGMENT-MAJOR layouts ----------
// Wtm2 panels: p = (g*8 + nb)*8 + kk          (nb: n-tile of 16, kk: k-chunk of 32)
//   offset kh*128 + l15*8 + e  <-  W_mid[g][i][o]*w_inp[g][i],
//   o = nb*16 + l15, i = kk*32 + kh*8 + e     (512 ushorts = 1 KB per panel)
// Wtr2 panels: q = (g*16 + nb)*4 + kk2
//   offset kh*128 + l15*8 + e  <-  W_root[k][o],
//   o = nb*16 + l15, k = g*128 + kk2*32 + kh*8 + e
//
// ws layout: Wtm2 1MB @0 | Wtr2 1MB @1MB | bias_eff @2MB | part @4MB

__global__ __launch_bounds__(256) void prep(const float* __restrict__ w_inp,
                                            const float* __restrict__ pbias,
                                            const float* __restrict__ W_mid,
                                            const float* __restrict__ b_mid,
                                            const float* __restrict__ W_root,
                                            ushort_t* __restrict__ Wtm2,
                                            ushort_t* __restrict__ Wtr2,
                                            float* __restrict__ bias_eff) {
  __shared__ float tl[32][33];
  __shared__ float red[256];
  const int b = blockIdx.x, t = threadIdx.x;
  const int tx = t & 31, ty = t >> 5;              // load-phase coords

  if (b < 512) {
    // per-g 256(i) x 128(o), 32x32 tiles: coalesced load+fold, frag-major store
    const int g = b >> 5, tile = b & 31;
    const int i0 = (tile >> 2) * 32, o0 = (tile & 3) * 32;
#pragma unroll
    for (int r = 0; r < 4; ++r) {
      const int il = ty * 4 + r;
      tl[il][tx] = W_mid[(g << 15) + (i0 + il) * 128 + o0 + tx] * w_inp[g * 256 + i0 + il];
    }
    __syncthreads();
    const int nl = t >> 3, s = t & 7;              // store-phase coords
    const int o = o0 + nl, nb = o >> 4, l15 = o & 15;
    const int kk = i0 >> 5;                        // i0 is 32-aligned
    const int iloc = s * 4, kh = iloc >> 3, e0 = iloc & 7;
    const uint32 lo = (uint32)f2bf_bits(tl[iloc + 0][nl]) |
                      ((uint32)f2bf_bits(tl[iloc + 1][nl]) << 16);
    const uint32 hi = (uint32)f2bf_bits(tl[iloc + 2][nl]) |
                      ((uint32)f2bf_bits(tl[iloc + 3][nl]) << 16);
    uint2* dst = (uint2*)(Wtm2 + (size_t)(((g * 8 + nb) * 8 + kk) * 512 + kh * 128 + l15 * 8 + e0));
    *dst = make_uint2(lo, hi);
  } else if (b < 1024) {
    // 2048(k) x 256(o), 32x32 tiles
    const int bb = b - 512;
    const int k0 = (bb >> 3) * 32, o0 = (bb & 7) * 32;
#pragma unroll
    for (int r = 0; r < 4; ++r) {
      const int kl = ty * 4 + r;
      tl[kl][tx] = W_root[(k0 + kl) * 256 + o0 + tx];
    }
    __syncthreads();
    const int nl = t >> 3, s = t & 7;
    const int o = o0 + nl, nb = o >> 4, l15 = o & 15;
    const int g = k0 >> 7, kk2 = (k0 >> 5) & 3;    // k0 is 32-aligned
    const int iloc = s * 4, kh = iloc >> 3, e0 = iloc & 7;
    const uint32 lo = (uint32)f2bf_bits(tl[iloc + 0][nl]) |
                      ((uint32)f2bf_bits(tl[iloc + 1][nl]) << 16);
    const uint32 hi = (uint32)f2bf_bits(tl[iloc + 2][nl]) |
                      ((uint32)f2bf_bits(tl[iloc + 3][nl]) << 16);
    uint2* dst = (uint2*)(Wtr2 + (size_t)(((g * 16 + nb) * 4 + kk2) * 512 + kh * 128 + l15 * 8 + e0));
    *dst = make_uint2(lo, hi);
  } else {
    // bias_eff[g][o] = b_mid[g][o] + sum_i pbias[g*4 + i>>6] * W_mid[g][i][o]
    const int g = b - 1024;
    const int o = t & 127, ih = t >> 7;
    const float* wp = W_mid + (g << 15) + ih * 128 * 128 + o;
    const float pb0 = pbias[g * 4 + ih * 2];
    const float pb1 = pbias[g * 4 + ih * 2 + 1];
    float s = 0.f;
#pragma unroll 8
    for (int ii = 0; ii < 128; ++ii) s += (ii < 64 ? pb0 : pb1) * wp[ii * 128];
    red[t] = s;
    __syncthreads();
    if (ih == 0) bias_eff[g * 128 + o] = b_mid[g * 128 + o] + red[o] + red[128 + o];
  }
}

// ---------- fused mid+root ----------
// v6: M=64, 8 waves, split-K x2, grid 512.
// SPILL FIX: v5's __launch_bounds__(512,4) empirically behaved as 4 BLOCKS/CU
// (CUDA minBlocks semantics): VGPR_Count=64 = 512 regs / 8 waves-per-SIMD, and
// WRITE_SIZE showed ~170 MB of scratch-spill traffic (200 MB vs 32 expected).
// (512,2) -> 128-VGPR cap = the intended 2 blocks/CU. To actually FIT 128
// without spills, root-B rounds 0/1 preload moved to AFTER the mid loop (rb no
// longer live across it; peak live set ~120). rb is still issued before the
// epilogue+BAR(C), so its L2 latency is covered; waits on rb drain the older
// rx prefetch early, which is harmless (rx isn't consumed until conv(g+1)).

template <bool SPLIT>
__global__ __launch_bounds__(512, 2) void fused(const float* __restrict__ x,
                                                const ushort_t* __restrict__ Wtm2,
                                                const ushort_t* __restrict__ Wtr2,
                                                const float* __restrict__ bias_eff,
                                                const float* __restrict__ b_root,
                                                float* __restrict__ dst) {
  constexpr int GROUPS = SPLIT ? 8 : 16;

  __shared__ __align__(16) ushort_t sX[64 * 264];   // 33.8 KB
  __shared__ __align__(16) ushort_t sMid[64 * 136]; // 17.4 KB

  const int t = threadIdx.x;
  const int lane = t & 63;
  const int w = __builtin_amdgcn_readfirstlane(t >> 6);   // wave 0..7
  const int tile = SPLIT ? (int)(blockIdx.x >> 1) : (int)blockIdx.x;
  const int h = SPLIT ? (int)(blockIdx.x & 1) : 0;
  const int G0 = h * 8;
  const int m0 = tile * 64;
  const int l15 = lane & 15;
  const int kh = lane >> 4;          // 0..3

  // x staging: thread t handles row xr = t>>3 (0..63), float4-slot xq = t&7
  const int xr = t >> 3, xq = t & 7;
  const float* xbase = x + (size_t)(m0 + xr) * 4096 + (size_t)G0 * 256 + xq * 4;
  uint32* sxw = (uint32*)(sX + xr * 264 + xq * 4);

  // A-frag LDS read bases
  const ushort_t* sxa = sX + l15 * 264 + kh * 8;    // + af*16*264 + kk*32
  const ushort_t* sma = sMid + l15 * 136 + kh * 8;  // + af*16*136 + kk2*32

  // wave-uniform weight bases (SGPR) + one per-lane element offset
  const ushort_t* wtm_u = Wtm2 + (((size_t)G0) << 15) + w * 4096;  // + g*32768 + kk*512 + wlo
  const ushort_t* wtr_u = Wtr2 + (((size_t)G0) << 15) + w * 4096;  // + g*32768 + (ni*4+kk2)*512 + wlo
  const int wlo = lane * 8;

  float4 rx[8];
  floatx4 racc[4][2] = {};

  // prologue: x for local group 0
#pragma unroll
  for (int p = 0; p < 8; ++p) rx[p] = *(const float4*)(xbase + p * 32);

#pragma unroll 1
  for (int g = 0; g < GROUPS; ++g) {
    const int gw = g << 15;

    // ---- issue this group's mid weight loads first (counted waits only) ----
    short8 mb[4];
#pragma unroll
    for (int kk = 0; kk < 4; ++kk) mb[kk] = *(const short8*)(wtm_u + gw + kk * 512 + wlo);
    const float bias = bias_eff[(G0 + g) * 128 + w * 16 + l15];

    // ---- convert rx (group g) -> sX, round-half-up + byte-perm pack ----
#pragma unroll
    for (int p = 0; p < 8; ++p) {
      uint32 bx = __builtin_bit_cast(uint32, rx[p].x) + 0x8000u;
      uint32 by = __builtin_bit_cast(uint32, rx[p].y) + 0x8000u;
      uint32 bz = __builtin_bit_cast(uint32, rx[p].z) + 0x8000u;
      uint32 bw = __builtin_bit_cast(uint32, rx[p].w) + 0x8000u;
      uint32 lo = __builtin_amdgcn_perm(by, bx, 0x07060302u);
      uint32 hi = __builtin_amdgcn_perm(bw, bz, 0x07060302u);
      *(uint2*)(sxw + p * 16) = make_uint2(lo, hi);
    }

    // ---- prefetch next group's x (issued AFTER conv read rx: regs reused) ----
    if (g < GROUPS - 1) {
      const float* xn = xbase + (g + 1) * 256;
#pragma unroll
      for (int p = 0; p < 8; ++p) rx[p] = *(const float4*)(xn + p * 32);
    }
    __builtin_amdgcn_sched_barrier(0);  // keep rx issue here (not sunk past mid)

    BAR_LGKM();  // (B) sX ready; also sX WAR safe (all waves past mid(g-1) via C)

    // ---- mid GEMM: 64x16 per wave (4 row-frags x 1 n-frag), K=256 ----
    // B ring distance 4: load for kk+4 issued at kk -> ~4 iterations of cover.
    floatx4 macc[4] = {};
#pragma unroll
    for (int kk = 0; kk < 8; ++kk) {
      short8 a0 = *(const short8*)(sxa + 0 * 16 * 264 + kk * 32);
      short8 a1 = *(const short8*)(sxa + 1 * 16 * 264 + kk * 32);
      short8 a2 = *(const short8*)(sxa + 2 * 16 * 264 + kk * 32);
      short8 a3 = *(const short8*)(sxa + 3 * 16 * 264 + kk * 32);
      short8 b = mb[kk & 3];
      if (kk < 4) mb[kk & 3] = *(const short8*)(wtm_u + gw + (kk + 4) * 512 + wlo);
      macc[0] = MFMA16(a0, b, macc[0]);
      macc[1] = MFMA16(a1, b, macc[1]);
      macc[2] = MFMA16(a2, b, macc[2]);
      macc[3] = MFMA16(a3, b, macc[3]);
    }

    __builtin_amdgcn_sched_barrier(0);  // mid loop done before rb issue

    // ---- root B rounds 0,1 preload (AFTER mid: not live across it) ----
    short8 rb[2][2];
#pragma unroll
    for (int ni = 0; ni < 2; ++ni) rb[0][ni] = *(const short8*)(wtr_u + gw + (ni * 4 + 0) * 512 + wlo);
#pragma unroll
    for (int ni = 0; ni < 2; ++ni) rb[1][ni] = *(const short8*)(wtr_u + gw + (ni * 4 + 1) * 512 + wlo);

    // ---- epilogue: bias + tanh -> sMid (bf16, root-A layout) ----
    {
      const int col = w * 16 + l15;
#pragma unroll
      for (int af = 0; af < 4; ++af)
#pragma unroll
        for (int r = 0; r < 4; ++r) {
          const int row = af * 16 + kh * 4 + r;
          sMid[row * 136 + col] = (ushort_t)f2bf_bits(tanh_fast(macc[af][r] + bias));
        }
    }

    BAR_LGKM();  // (C) sMid ready

    // ---- root partial: 64x32 per wave (4 row-frags x 2 n-frags), K=128 ----
#pragma unroll
    for (int kk2 = 0; kk2 < 4; ++kk2) {
      short8 a0 = *(const short8*)(sma + 0 * 16 * 136 + kk2 * 32);
      short8 a1 = *(const short8*)(sma + 1 * 16 * 136 + kk2 * 32);
      short8 a2 = *(const short8*)(sma + 2 * 16 * 136 + kk2 * 32);
      short8 a3 = *(const short8*)(sma + 3 * 16 * 136 + kk2 * 32);
      short8 b0 = rb[kk2 & 1][0], b1 = rb[kk2 & 1][1];
      if (kk2 < 2) {  // stream rounds 2,3; no dead tail loads
#pragma unroll
        for (int ni = 0; ni < 2; ++ni)
          rb[kk2 & 1][ni] = *(const short8*)(wtr_u + gw + (ni * 4 + kk2 + 2) * 512 + wlo);
      }
      racc[0][0] = MFMA16(a0, b0, racc[0][0]);
      racc[0][1] = MFMA16(a0, b1, racc[0][1]);
      racc[1][0] = MFMA16(a1, b0, racc[1][0]);
      racc[1][1] = MFMA16(a1, b1, racc[1][1]);
      racc[2][0] = MFMA16(a2, b0, racc[2][0]);
      racc[2][1] = MFMA16(a2, b1, racc[2][1]);
      racc[3][0] = MFMA16(a3, b0, racc[3][0]);
      racc[3][1] = MFMA16(a3, b1, racc[3][1]);
    }
  }

  // ---- final store ----
  float* o = SPLIT ? dst + (size_t)h * (16384 * 256) : dst;
#pragma unroll
  for (int ni = 0; ni < 2; ++ni) {
    const int col = w * 32 + ni * 16 + l15;
    const float br = SPLIT ? 0.0f : b_root[col];
#pragma unroll
    for (int af = 0; af < 4; ++af)
#pragma unroll
      for (int r = 0; r < 4; ++r) {
        const int row = m0 + af * 16 + kh * 4 + r;
        o[(size_t)row * 256 + col] = racc[af][ni][r] + br;
      }
  }
}

// ---------- split-K reduce: out = p0 + p1 + b_root ----------

__global__ __launch_bounds__(256) void reducek(const float* __restrict__ part,
                                               const float* __restrict__ b_root,
                                               float* __restrict__ out) {
  const int i = blockIdx.x * 256 + threadIdx.x;   // float4 index, 1,048,576 total
  float4 a = ((const float4*)part)[i];
  float4 c = ((const float4*)(part + (size_t)16384 * 256))[i];
  float4 br = ((const float4*)b_root)[i & 63];
  float4 r;
  r.x = a.x + c.x + br.x;
  r.y = a.y + c.y + br.y;
  r.z = a.z + c.z + br.z;
  r.w = a.w + c.w + br.w;
  ((float4*)out)[i] = r;
}

// ---------- launch ----------

extern "C" void kernel_launch(void* const* d_in, const int* in_sizes, int n_in,
                              void* d_out, int out_size, void* d_ws, size_t ws_size,
                              hipStream_t stream) {
  const float* x      = (const float*)d_in[0];
  const float* w_inp  = (const float*)d_in[1];
  const float* pbias  = (const float*)d_in[2];
  const float* W_mid  = (const float*)d_in[3];
  const float* b_mid  = (const float*)d_in[4];
  const float* W_root = (const float*)d_in[5];
  const float* b_root = (const float*)d_in[6];
  float* out = (float*)d_out;

  char* ws = (char*)d_ws;
  ushort_t* Wtm2     = (ushort_t*)(ws);
  ushort_t* Wtr2     = (ushort_t*)(ws + (1 << 20));
  float*    bias_eff = (float*)   (ws + (2 << 20));
  float*    part     = (float*)   (ws + (4 << 20));

  const size_t need = (size_t)(4 << 20) + 2ull * 16384 * 256 * 4;
  const bool split = ws_size >= need;

  prep<<<dim3(1040), dim3(256), 0, stream>>>(w_inp, pbias, W_mid, b_mid, W_root, Wtm2, Wtr2, bias_eff);
  if (split) {
    fused<true><<<dim3(512), dim3(512), 0, stream>>>(x, Wtm2, Wtr2, bias_eff, b_root, part);
    reducek<<<dim3(4096), dim3(256), 0, stream>>>(part, b_root, out);
  } else {
    fused<false><<<dim3(256), dim3(512), 0, stream>>>(x, Wtm2, Wtr2, bias_eff, b_root, out);
  }
}